// Round 10
// baseline (512.583 us; speedup 1.0000x reference)
//
#include <hip/hip_runtime.h>
#include <stdint.h>

// Problem constants (fixed by setup_inputs)
#define PN     512
#define NFREE  50000
#define NCND   100000
#define NNODE  100512
#define NEDGE  300000
#define KK     10
#define NLOOP  5
#define EPSV   1e-5f

#define GRID   128
#define NCELL  (GRID*GRID)

// fixed spatial-hash bounds: candidates ~N(0,1); clamping keeps exactness
#define XMINF  (-6.f)
#define YMINF  (-6.f)
#define SPANF  12.f
#define IVCW   ((float)GRID / SPANF)

#define HSIZE  8192
#define HMASK  (HSIZE-1)
#define E0CAP  4096
#define EMPTYK 0xFFFFFFFFFFFFFFFFull

#define NCB    ((NCND+255)/256)    // 391
#define NEB    ((NEDGE+255)/256)   // 1172
#define LOOPB  128                 // blocks in k_loops (<=256 CUs -> co-resident)

// workspace layout (bytes) — ~2.8 MB
#define OFF_HASH    ((size_t)0)
#define OFF_CPOS    (OFF_HASH    + (size_t)HSIZE*8)
#define OFF_SCND    (OFF_CPOS    + 800000)               // float4/cand, cell-sorted
#define OFF_CSTART  (OFF_SCND    + 1600000)              // NCELL+1 ints
#define OFF_COFS    (OFF_CSTART  + 65600)
#define OFF_MOM     (OFF_COFS    + 65600)                // 10 floats (cand moments)
#define OFF_BAR     (OFF_MOM     + 64)                   // 2 ints: cnt, gen
#define OFF_PMOM    (OFF_BAR     + 64)                   // 5 floats (path moments)
#define OFF_WCU     (OFF_PMOM    + 64)
#define OFF_WCV     (OFF_WCU     + 4096)
#define OFF_BU      (OFF_WCV     + 4096)
#define OFF_BV      (OFF_BU      + 128)
#define OFF_CPATH   (OFF_BV      + 128)
#define OFF_CFREE   (OFF_CPATH   + 128)
#define OFF_CCOL    (OFF_CFREE   + 128)
#define OFF_PATH    (OFF_CCOL    + 128)                  // 16-aligned
#define OFF_E0S     (OFF_PATH    + 4096)
#define OFF_E0D     (OFF_E0S     + (size_t)E0CAP*4)
#define OFF_DEG0    (OFF_E0D     + (size_t)E0CAP*4)
#define OFF_E0C     (OFF_DEG0    + 2048)
#define OFF_E0START (OFF_E0C     + 64)                   // 513 ints (pad 2112)
#define OFF_E0OFS   (OFF_E0START + 2112)
#define OFF_E0CSRS  (OFF_E0OFS   + 2048)                 // E0CAP ints

#define WS_F(o)  ((float*)(ws + (o)))
#define WS_I(o)  ((int*)(ws + (o)))
#define WS_H(o)  ((unsigned long long*)(ws + (o)))

#define AG_LD(p)    __hip_atomic_load((p), __ATOMIC_RELAXED, __HIP_MEMORY_SCOPE_AGENT)
#define AG_ST(p,v)  __hip_atomic_store((p), (v), __ATOMIC_RELAXED, __HIP_MEMORY_SCOPE_AGENT)

__device__ __forceinline__ bool lexless(float da, int ia, float db, int ib) {
  return (da < db) || (da == db && ia < ib);
}

__device__ __forceinline__ uint32_t hslot(unsigned long long key) {
  return (uint32_t)((key * 0x9E3779B97F4A7C15ull) >> 40) & HMASK;
}

// sense-reversing grid barrier via device-scope atomics (decoupled-lookback
// pattern — coherent across XCDs). 128 blocks <= 256 CUs -> no deadlock.
__device__ __forceinline__ void gridbar(char* ws) {
  __syncthreads();
  if (threadIdx.x == 0) {
    int* cnt = WS_I(OFF_BAR);
    int* gen = WS_I(OFF_BAR) + 1;
    int g = __hip_atomic_load(gen, __ATOMIC_RELAXED, __HIP_MEMORY_SCOPE_AGENT);
    int a = __hip_atomic_fetch_add(cnt, 1, __ATOMIC_ACQ_REL, __HIP_MEMORY_SCOPE_AGENT);
    if (a == LOOPB - 1) {
      __hip_atomic_store(cnt, 0, __ATOMIC_RELAXED, __HIP_MEMORY_SCOPE_AGENT);
      __hip_atomic_store(gen, g + 1, __ATOMIC_RELEASE, __HIP_MEMORY_SCOPE_AGENT);
    } else {
      while (__hip_atomic_load(gen, __ATOMIC_ACQUIRE, __HIP_MEMORY_SCOPE_AGENT) == g)
        __builtin_amdgcn_s_sleep(8);
    }
  }
  __syncthreads();
}

// BN mean/rstd from analytic moments (cand moments in MOM + path moments pm*)
__device__ __forceinline__ void bn_from_moments(const char* ws,
    float w0, float w1, float cp, float clsF, float clsC,
    float pm0, float pm1, float pm00, float pm11, float pm01,
    float* meano, float* rstdo) {
  const float* M = (const float*)(ws + OFF_MOM);
  float sF0=M[0], sF1=M[1], sF00=M[2], sF11=M[3], sF01=M[4];
  float sC0=M[5], sC1=M[6], sC00=M[7], sC11=M[8], sC01=M[9];
  const float NC = (float)(NCND - NFREE);
  float sh  = w0*(sF0+sC0+pm0) + w1*(sF1+sC1+pm1)
            + (float)NFREE*clsF + NC*clsC + (float)PN*cp;
  float sh2 = w0*w0*(sF00+sC00+pm00) + w1*w1*(sF11+sC11+pm11)
            + 2.f*w0*w1*(sF01+sC01+pm01)
            + 2.f*w0*(clsF*sF0 + clsC*sC0 + cp*pm0)
            + 2.f*w1*(clsF*sF1 + clsC*sC1 + cp*pm1)
            + (float)NFREE*clsF*clsF + NC*clsC*clsC + (float)PN*cp*cp;
  float mean = sh  * (1.f / NNODE);
  float ex2  = sh2 * (1.f / NNODE);
  float var  = ex2 - mean * mean;
  *meano = mean;
  *rstdo = 1.0f / sqrtf(var + EPSV);
}

#define INSERT10(d2v, jv)                                                  \
  if (lexless((d2v), (jv), bd[9], bi[9])) {                                \
    bool placed = false;                                                   \
    _Pragma("unroll")                                                      \
    for (int k = 9; k > 0; k--) {                                          \
      bool shift = !placed && lexless((d2v), (jv), bd[k-1], bi[k-1]);      \
      bool here  = !placed && !shift;                                      \
      if (here)       { bd[k] = (d2v); bi[k] = (jv); placed = true; }      \
      else if (shift) { bd[k] = bd[k-1]; bi[k] = bi[k-1]; }                \
    }                                                                      \
    if (!placed) { bd[0] = (d2v); bi[0] = (jv); }                          \
  }

#define MERGEPOP() do {                                                    \
    float cd[10]; int ci[10];                                              \
    _Pragma("unroll")                                                      \
    for (int k = 0; k < 10; k++) { cd[k] = bd[k]; ci[k] = bi[k]; }         \
    _Pragma("unroll")                                                      \
    for (int r = 0; r < 10; r++) {                                         \
      float md = cd[0]; int mi = ci[0];                                    \
      _Pragma("unroll")                                                    \
      for (int off = 32; off >= 1; off >>= 1) {                            \
        float od = __shfl_xor(md, off);                                    \
        int   oi = __shfl_xor(mi, off);                                    \
        if (lexless(od, oi, md, mi)) { md = od; mi = oi; }                 \
      }                                                                    \
      bool win = (cd[0] == md) && (ci[0] == mi);                           \
      if (win) {                                                           \
        _Pragma("unroll")                                                  \
        for (int k = 0; k < 9; k++) { cd[k] = cd[k+1]; ci[k] = ci[k+1]; }  \
        cd[9] = 3.4e38f; ci[9] = 0x7FFFFFFF;                               \
      }                                                                    \
      if (lane == r) selIdx = mi;                                          \
      cur10d = md;                                                         \
    }                                                                      \
  } while (0)

#define SCAN_BOX(xA, xB, yA, yB) do {                                      \
    for (int _y = (yA); _y <= (yB); _y++) {                                \
      int _s = cst[_y*GRID + (xA)], _e = cst[_y*GRID + (xB) + 1];          \
      for (int _t = _s + lane; _t < _e; _t += 64) {                        \
        float4 _q = scnd[_t];                                              \
        float _d2 = (psq + _q.z) - 2.f * fmaf(p1, _q.y, p0 * _q.x);        \
        int _j = __float_as_int(_q.w);                                     \
        INSERT10(_d2, _j);                                                 \
      }                                                                    \
    }                                                                      \
  } while (0)

// ---------------- setup kernels ----------------

__global__ __launch_bounds__(256) void k_init0(char* __restrict__ ws,
                                               const float* __restrict__ path_in) {
  unsigned i = blockIdx.x * 256u + threadIdx.x;       // grid = 65 → 16640 ids
  if (i < HSIZE)   WS_H(OFF_HASH)[i] = EMPTYK;
  if (i < NCELL+1) WS_I(OFF_CSTART)[i] = 0;
  if (i < 1024)    WS_F(OFF_PATH)[i] = path_in[i];
  if (i < 512)     WS_I(OFF_DEG0)[i] = 0;
  if (i < 16)      WS_F(OFF_MOM)[i] = 0.f;
  if (i < 2)       WS_I(OFF_BAR)[i] = 0;
  if (i == 0)      *WS_I(OFF_E0C) = 0;
}

// roles: b<NCB cand(pos/moments/hist) | b<NCB+NEB edge filter+dedup | last wprep
__global__ __launch_bounds__(256) void k_setupA(char* __restrict__ ws,
    const float* __restrict__ freep, const float* __restrict__ collp,
    const int* __restrict__ ei,
    const float* __restrict__ ncw1, const float* __restrict__ ncb1,
    const float* __restrict__ m0w1, const float* __restrict__ m0b1,
    const float* __restrict__ ncw2, const float* __restrict__ ncb2) {
  int b = blockIdx.x, tid = threadIdx.x;
  if (b < NCB) {
    __shared__ float s10[4][10];
    int j = b*256 + tid;
    bool valid = (j < NCND);
    float c0 = 0.f, c1 = 0.f;
    if (valid) {
      if (j < NFREE) { c0 = freep[2*j];          c1 = freep[2*j+1]; }
      else           { c0 = collp[2*(j-NFREE)];  c1 = collp[2*(j-NFREE)+1]; }
      ((float2*)(ws + OFF_CPOS))[j] = make_float2(c0, c1);
    }
    bool isF = valid && (j < NFREE), isC = valid && (j >= NFREE);
    float v[10];
    v[0]=isF?c0:0.f; v[1]=isF?c1:0.f; v[2]=isF?c0*c0:0.f; v[3]=isF?c1*c1:0.f; v[4]=isF?c0*c1:0.f;
    v[5]=isC?c0:0.f; v[6]=isC?c1:0.f; v[7]=isC?c0*c0:0.f; v[8]=isC?c1*c1:0.f; v[9]=isC?c0*c1:0.f;
    #pragma unroll
    for (int q = 0; q < 10; q++)
      #pragma unroll
      for (int off = 32; off >= 1; off >>= 1) v[q] += __shfl_xor(v[q], off);
    int wv = tid >> 6, lane = tid & 63;
    if (lane == 0) {
      #pragma unroll
      for (int q = 0; q < 10; q++) s10[wv][q] = v[q];
    }
    if (valid) {
      int cx = min(GRID-1, max(0, (int)((c0 - XMINF) * IVCW)));
      int cy = min(GRID-1, max(0, (int)((c1 - YMINF) * IVCW)));
      atomicAdd(&WS_I(OFF_CSTART)[cy*GRID + cx], 1);
    }
    __syncthreads();
    if (tid < 10)
      atomicAdd(&WS_F(OFF_MOM)[tid], s10[0][tid]+s10[1][tid]+s10[2][tid]+s10[3][tid]);
  } else if (b < NCB + NEB) {
    int e = (b - NCB)*256 + tid;
    if (e >= NEDGE) return;
    int src = ei[e], dst = ei[NEDGE + e];
    if (dst >= PN) return;                         // only dst<PN edges matter
    unsigned long long key = (unsigned long long)src * NNODE + (unsigned long long)dst;
    unsigned long long* hash = WS_H(OFF_HASH);
    uint32_t slot = hslot(key);
    for (;;) {
      unsigned long long prev = atomicCAS(&hash[slot], EMPTYK, key);
      if (prev == EMPTYK) {
        int pos = atomicAdd(WS_I(OFF_E0C), 1);
        if (pos < E0CAP) {
          WS_I(OFF_E0S)[pos] = src;
          WS_I(OFF_E0D)[pos] = dst;
          atomicAdd(&WS_I(OFF_DEG0)[dst], 1);
        }
        break;
      }
      if (prev == key) break;
      slot = (slot + 1) & HMASK;
    }
  } else {
    __shared__ float Wu[1024], Wv[1024];
    for (int it = 0; it < 4; it++) {
      int idx = it*256 + tid, k = idx >> 5, g = idx & 31;
      float a = m0w1[k*32+g], b2 = m0w1[(k+32)*32+g], c = m0w1[(k+64)*32+g];
      Wu[idx] = a + b2;  Wv[idx] = c - a;
    }
    __syncthreads();
    for (int it = 0; it < 4; it++) {
      int idx = it*256 + tid, k = idx >> 5, g = idx & 31;
      float au = 0.f, av = 0.f;
      #pragma unroll
      for (int f = 0; f < 32; f++) {
        float w2 = ncw2[k*32+f];
        au = fmaf(w2, Wu[f*32+g], au);
        av = fmaf(w2, Wv[f*32+g], av);
      }
      WS_F(OFF_WCU)[idx] = au;  WS_F(OFF_WCV)[idx] = av;
    }
    if (tid < 32) {
      float bu = 0.f, bv = 0.f;
      #pragma unroll
      for (int f = 0; f < 32; f++) {
        bu = fmaf(ncb2[f], Wu[f*32+tid], bu);
        bv = fmaf(ncb2[f], Wv[f*32+tid], bv);
      }
      WS_F(OFF_BU)[tid] = bu;
      WS_F(OFF_BV)[tid] = bv + m0b1[tid];        // fold mp0_b1 into dst-side
      WS_F(OFF_CPATH)[tid] = ncw1[64+tid]  + ncb1[tid];
      WS_F(OFF_CFREE)[tid] = ncw1[96+tid]  + ncb1[tid];
      WS_F(OFF_CCOL)[tid]  = ncw1[128+tid] + ncb1[tid];
    }
  }
}

// b==0: exclusive scan of cell counts | b==1: CSR build of fixed edges
__global__ __launch_bounds__(256) void k_scan2(char* __restrict__ ws) {
  int b = blockIdx.x, tid = threadIdx.x;
  if (b == 0) {
    __shared__ int part[256];
    int* cnt = WS_I(OFF_CSTART);
    int base = tid * (NCELL/256);
    int sum = 0;
    for (int k = 0; k < NCELL/256; k++) sum += cnt[base+k];
    part[tid] = sum;
    __syncthreads();
    for (int off = 1; off < 256; off <<= 1) {
      int t = (tid >= off) ? part[tid - off] : 0;
      __syncthreads();
      part[tid] += t;
      __syncthreads();
    }
    int run = part[tid] - sum;
    for (int k = 0; k < NCELL/256; k++) {
      int c = cnt[base+k];
      cnt[base+k] = run;
      WS_I(OFF_COFS)[base+k] = run;
      run += c;
    }
    if (tid == 255) cnt[NCELL] = run;
  } else {
    __shared__ int sc[512];
    sc[tid]     = WS_I(OFF_DEG0)[tid];
    sc[256+tid] = WS_I(OFF_DEG0)[256+tid];
    __syncthreads();
    if (tid == 0) {
      int run = 0;
      for (int i = 0; i < 512; i++) { int c = sc[i]; sc[i] = run; run += c; }
      WS_I(OFF_E0START)[512] = run;
    }
    __syncthreads();
    WS_I(OFF_E0START)[tid]     = sc[tid];
    WS_I(OFF_E0START)[256+tid] = sc[256+tid];
    WS_I(OFF_E0OFS)[tid]       = sc[tid];
    WS_I(OFF_E0OFS)[256+tid]   = sc[256+tid];
    __syncthreads();
    int n = *WS_I(OFF_E0C); if (n > E0CAP) n = E0CAP;
    for (int e = tid; e < n; e += 256) {
      int dst = WS_I(OFF_E0D)[e];
      int pos = atomicAdd(&WS_I(OFF_E0OFS)[dst], 1);
      WS_I(OFF_E0CSRS)[pos] = WS_I(OFF_E0S)[e];
    }
  }
}

__global__ __launch_bounds__(256) void k_scatter(char* __restrict__ ws) {
  int j = blockIdx.x * 256 + threadIdx.x;
  if (j >= NCND) return;
  float2 c = ((const float2*)(ws + OFF_CPOS))[j];
  int cx = min(GRID-1, max(0, (int)((c.x - XMINF) * IVCW)));
  int cy = min(GRID-1, max(0, (int)((c.y - YMINF) * IVCW)));
  int pos = atomicAdd(&WS_I(OFF_COFS)[cy*GRID + cx], 1);
  ((float4*)(ws + OFF_SCND))[pos] =
      make_float4(c.x, c.y, c.x*c.x + c.y*c.y, __int_as_float(j));
}

// ---------------- all 5 smoothing iterations in ONE dispatch ----------------
// 128 blocks x 256 threads (all co-resident); wave-per-node. Loop-carried
// state (path, moments) crosses blocks via agent-scope atomics + gridbar;
// bulky read-only data (SCND/cst/CSR/weights) stays L2-warm across iterations.
__global__ __launch_bounds__(256) void k_loops(char* __restrict__ ws,
    const float* __restrict__ ncw1, const float* __restrict__ gamma,
    const float* __restrict__ beta, const float* __restrict__ ncw2,
    const float* __restrict__ ncb2, const float* __restrict__ m0w2,
    const float* __restrict__ m0b2, const float* __restrict__ m1w1,
    const float* __restrict__ m1b1, const float* __restrict__ m1w2,
    const float* __restrict__ m1b2, const float* __restrict__ snw,
    const float* __restrict__ snb, float* __restrict__ outp) {
  __shared__ float sm[4][5];
  int tid = threadIdx.x, lane = tid & 63;
  int node = blockIdx.x*4 + (tid >> 6);
  float* pathg = WS_F(OFF_PATH);
  float* pmom  = WS_F(OFF_PMOM);
  const float4* scnd = (const float4*)(ws + OFF_SCND);
  const int* cst = WS_I(OFF_CSTART);

  // own node position (registers across iterations)
  float p0 = AG_LD(&pathg[2*node]), p1 = AG_LD(&pathg[2*node+1]);

  int fA = lane & 31;
  float w0 = ncw1[fA], w1 = ncw1[32+fA], cp = WS_F(OFF_CPATH)[fA];
  float clsF = WS_F(OFF_CFREE)[fA], clsC = WS_F(OFF_CCOL)[fA];
  float gm = gamma[fA], bt = beta[fA];
  const float* wcu = WS_F(OFF_WCU); const float* wcv = WS_F(OFF_WCV);
  float buf = WS_F(OFF_BU)[fA], bvf = WS_F(OFF_BV)[fA];
  int s0 = WS_I(OFF_E0START)[node], s1 = WS_I(OFF_E0START)[node+1];

  for (int l = 0; l < NLOOP; l++) {
    // barrier A: previous iteration's path stores visible
    gridbar(ws);
    // block 0 computes path moments (fresh path via agent loads)
    if (blockIdx.x == 0) {
      float q0a = AG_LD(&pathg[2*tid]),       q1a = AG_LD(&pathg[2*tid+1]);
      float q0b = AG_LD(&pathg[2*(tid+256)]), q1b = AG_LD(&pathg[2*(tid+256)+1]);
      float m0 = q0a+q0b, m1 = q1a+q1b;
      float m00 = q0a*q0a+q0b*q0b, m11 = q1a*q1a+q1b*q1b, m01 = q0a*q1a+q0b*q1b;
      #pragma unroll
      for (int off = 32; off >= 1; off >>= 1) {
        m0+=__shfl_xor(m0,off); m1+=__shfl_xor(m1,off); m00+=__shfl_xor(m00,off);
        m11+=__shfl_xor(m11,off); m01+=__shfl_xor(m01,off);
      }
      int wv = tid >> 6;
      if (lane == 0) { sm[wv][0]=m0; sm[wv][1]=m1; sm[wv][2]=m00; sm[wv][3]=m11; sm[wv][4]=m01; }
      __syncthreads();
      if (tid < 5) AG_ST(&pmom[tid], sm[0][tid]+sm[1][tid]+sm[2][tid]+sm[3][tid]);
      __syncthreads();
    }
    // barrier B: moments visible
    gridbar(ws);
    float M0 = AG_LD(&pmom[0]), M1 = AG_LD(&pmom[1]), M2 = AG_LD(&pmom[2]);
    float M3 = AG_LD(&pmom[3]), M4 = AG_LD(&pmom[4]);

    float psq = p0*p0 + p1*p1;
    int cx = min(GRID-1, max(0, (int)((p0 - XMINF) * IVCW)));
    int cy = min(GRID-1, max(0, (int)((p1 - YMINF) * IVCW)));

    // ---- kNN phase A: grow square box until >=10 pts (prefix counts) ----
    int R = 1, xL, xR, yL, yR;
    for (;;) {
      xL = max(cx - R, 0); xR = min(cx + R, GRID-1);
      yL = max(cy - R, 0); yR = min(cy + R, GRID-1);
      int cnt = 0;
      for (int y = yL + lane; y <= yR; y += 64)
        cnt += cst[y*GRID + xR + 1] - cst[y*GRID + xL];
      #pragma unroll
      for (int off = 32; off >= 1; off >>= 1) cnt += __shfl_xor(cnt, off);
      if (cnt >= KK || R >= GRID) break;
      R <<= 1;
    }

    float bd[10]; int bi[10];
    #pragma unroll
    for (int k = 0; k < 10; k++) { bd[k] = 3.4e38f; bi[k] = 0x7FFFFFFF; }
    float cur10d = 3.4e38f;
    int selIdx = 0x7FFFFFFF;

    // ---- phase B: seed box scan ----
    SCAN_BOX(xL, xR, yL, yR);
    MERGEPOP();

    // ---- phase C: exact re-scan of cells overlapping [p +- r] ----
    float r = sqrtf(cur10d) * 1.000002f;
    int xL2 = min(GRID-1, max(0, (int)((p0 - r - XMINF) * IVCW)));
    int xR2 = min(GRID-1, max(0, (int)((p0 + r - XMINF) * IVCW)));
    int yL2 = min(GRID-1, max(0, (int)((p1 - r - YMINF) * IVCW)));
    int yR2 = min(GRID-1, max(0, (int)((p1 + r - YMINF) * IVCW)));
    #pragma unroll
    for (int k = 0; k < 10; k++) { bd[k] = 3.4e38f; bi[k] = 0x7FFFFFFF; }
    SCAN_BOX(xL2, xR2, yL2, yR2);
    MERGEPOP();

    // ---- dedup vs fixed edges; ballot -> wave-uniform keep mask ----
    int keep = 0;
    if (lane < KK) {
      int srcg = selIdx + PN;
      keep = 1;
      for (int t = s0; t < s1; t++)
        if (WS_I(OFF_E0CSRS)[t] == srcg) { keep = 0; break; }
    }
    unsigned long long kmask = __ballot(keep);
    int deg = (int)__popcll(kmask) + (s1 - s0);

    // ---- analytic BN ----
    float mean, rstd;
    bn_from_moments(ws, w0, w1, cp, clsF, clsC, M0, M1, M2, M3, M4, &mean, &rstd);

    // ---- xn_dst and v[dst] ----
    float hD = fmaf(p1, w1, fmaf(p0, w0, cp));
    float xnd = fmaf((hD - mean) * rstd, gm, bt);
    xnd = xnd > 0.f ? xnd : 0.f;
    float av = bvf;
    #pragma unroll
    for (int m = 0; m < 32; m++) av = fmaf(__shfl(xnd, m), wcv[m*32+fA], av);

    // ---- S: kept kNN edges ----
    float S = 0.f;
    for (int k = 0; k < KK; k++) {
      if (!((kmask >> k) & 1ull)) continue;
      int jj = __shfl(selIdx, k);
      float c0 = WS_F(OFF_CPOS)[2*jj], c1 = WS_F(OFF_CPOS)[2*jj+1];
      float clsv = (jj < NFREE) ? clsF : clsC;
      float h = fmaf(c1, w1, fmaf(c0, w0, clsv));
      float xnf = fmaf((h - mean) * rstd, gm, bt);
      xnf = xnf > 0.f ? xnf : 0.f;
      float au = buf;
      #pragma unroll
      for (int m = 0; m < 32; m++) au = fmaf(__shfl(xnf, m), wcu[m*32+fA], au);
      float rr = au + av;
      if (rr > 0.f) S += rr;
    }
    // ---- S: fixed edges (src may be path node -> fresh agent load) ----
    for (int t = s0; t < s1; t++) {
      int src = WS_I(OFF_E0CSRS)[t];
      float q0, q1, clsv;
      if (src < PN) {
        q0 = AG_LD(&pathg[2*src]); q1 = AG_LD(&pathg[2*src+1]); clsv = cp;
      } else {
        int jj = src - PN;
        q0 = WS_F(OFF_CPOS)[2*jj]; q1 = WS_F(OFF_CPOS)[2*jj+1];
        clsv = (jj < NFREE) ? clsF : clsC;
      }
      float h = fmaf(q1, w1, fmaf(q0, w0, clsv));
      float xnf = fmaf((h - mean) * rstd, gm, bt);
      xnf = xnf > 0.f ? xnf : 0.f;
      float au = buf;
      #pragma unroll
      for (int m = 0; m < 32; m++) au = fmaf(__shfl(xnf, m), wcu[m*32+fA], au);
      float rr = au + av;
      if (rr > 0.f) S += rr;
    }

    // ---- epilogue: four 32x32 GEMVs via shfl-dots ----
    float o = (float)deg * m0b2[fA];
    #pragma unroll
    for (int k = 0; k < 32; k++) o = fmaf(__shfl(S, k), m0w2[k*32+fA], o);
    float t1 = m1b1[fA];
    #pragma unroll
    for (int k = 0; k < 32; k++) t1 = fmaf(__shfl(o, k), m1w1[k*32+fA], t1);
    t1 = t1 > 0.f ? t1 : 0.f;
    float g2 = m1b2[fA];
    #pragma unroll
    for (int k = 0; k < 32; k++) g2 = fmaf(__shfl(t1, k), m1w2[k*32+fA], g2);
    float x = ncb2[fA];
    #pragma unroll
    for (int k = 0; k < 32; k++) x = fmaf(__shfl(xnd, k), ncw2[k*32+fA], x);
    float hh = x + g2;
    float r0 = hh * snw[2*fA], r1 = hh * snw[2*fA+1];
    #pragma unroll
    for (int off = 16; off >= 1; off >>= 1) {
      r0 += __shfl_xor(r0, off);
      r1 += __shfl_xor(r1, off);
    }
    // r0/r1 uniform across the wave (both 32-halves identical)
    float np0, np1;
    if (node == 0 || node == PN-1) { np0 = p0; np1 = p1; }   // endpoints fixed
    else { np0 = snb[0] + r0; np1 = snb[1] + r1; }
    if (lane == 0) {
      AG_ST(&pathg[2*node], np0);
      AG_ST(&pathg[2*node+1], np1);
      outp[2*node]   = np0;
      outp[2*node+1] = np1;
    }
    p0 = np0; p1 = np1;
  }
}

// ---------------- host launch ----------------

extern "C" void kernel_launch(void* const* d_in, const int* in_sizes, int n_in,
                              void* d_out, int out_size, void* d_ws, size_t ws_size,
                              hipStream_t stream) {
  const float* path  = (const float*)d_in[0];
  const float* freep = (const float*)d_in[1];
  const float* collp = (const float*)d_in[2];
  const int*   ei    = (const int*)d_in[4];
  const float* ncw1  = (const float*)d_in[6];
  const float* ncb1  = (const float*)d_in[7];
  const float* gamma = (const float*)d_in[8];
  const float* beta  = (const float*)d_in[9];
  const float* ncw2  = (const float*)d_in[10];
  const float* ncb2  = (const float*)d_in[11];
  const float* m0w1  = (const float*)d_in[12];
  const float* m0b1  = (const float*)d_in[13];
  const float* m0w2  = (const float*)d_in[14];
  const float* m0b2  = (const float*)d_in[15];
  const float* m1w1  = (const float*)d_in[16];
  const float* m1b1  = (const float*)d_in[17];
  const float* m1w2  = (const float*)d_in[18];
  const float* m1b2  = (const float*)d_in[19];
  const float* snw   = (const float*)d_in[20];
  const float* snb   = (const float*)d_in[21];
  char* ws = (char*)d_ws;

  k_init0  <<<65, 256, 0, stream>>>(ws, path);
  k_setupA <<<NCB + NEB + 1, 256, 0, stream>>>(ws, freep, collp, ei,
                                               ncw1, ncb1, m0w1, m0b1, ncw2, ncb2);
  k_scan2  <<<2, 256, 0, stream>>>(ws);
  k_scatter<<<NCB, 256, 0, stream>>>(ws);

  k_loops<<<LOOPB, 256, 0, stream>>>(ws, ncw1, gamma, beta, ncw2, ncb2,
                                     m0w2, m0b2, m1w1, m1b1, m1w2, m1b2,
                                     snw, snb, (float*)d_out);
}

// Round 11
// 354.618 us; speedup vs baseline: 1.4454x; 1.4454x over previous
//
#include <hip/hip_runtime.h>
#include <stdint.h>

// Problem constants (fixed by setup_inputs)
#define PN     512
#define NFREE  50000
#define NCND   100000
#define NNODE  100512
#define NEDGE  300000
#define KK     10
#define NLOOP  5
#define EPSV   1e-5f

#define GRID   128
#define NCELL  (GRID*GRID)

// fixed spatial-hash bounds: candidates ~N(0,1); clamping keeps exactness
#define XMINF  (-6.f)
#define YMINF  (-6.f)
#define SPANF  12.f
#define IVCW   ((float)GRID / SPANF)

#define HSIZE  8192
#define HMASK  (HSIZE-1)
#define E0CAP  4096
#define EMPTYK 0xFFFFFFFFFFFFFFFFull

#define NCB    ((NCND+255)/256)    // 391
#define NEB    ((NEDGE+255)/256)   // 1172

// workspace layout (bytes) — ~2.8 MB
#define OFF_HASH    ((size_t)0)
#define OFF_CPOS    (OFF_HASH    + (size_t)HSIZE*8)
#define OFF_SCND    (OFF_CPOS    + 800000)               // float4/cand, cell-sorted
#define OFF_CSTART  (OFF_SCND    + 1600000)              // NCELL+1 ints
#define OFF_COFS    (OFF_CSTART  + 65600)
#define OFF_MOM     (OFF_COFS    + 65600)                // 10 floats (cand moments)
#define OFF_WCU     (OFF_MOM     + 64)
#define OFF_WCV     (OFF_WCU     + 4096)
#define OFF_BU      (OFF_WCV     + 4096)
#define OFF_BV      (OFF_BU      + 128)
#define OFF_CPATH   (OFF_BV      + 128)
#define OFF_CFREE   (OFF_CPATH   + 128)
#define OFF_CCOL    (OFF_CFREE   + 128)
#define OFF_PATH    (OFF_CCOL    + 128)                  // 16-aligned
#define OFF_E0S     (OFF_PATH    + 4096)
#define OFF_E0D     (OFF_E0S     + (size_t)E0CAP*4)
#define OFF_DEG0    (OFF_E0D     + (size_t)E0CAP*4)
#define OFF_E0C     (OFF_DEG0    + 2048)
#define OFF_E0START (OFF_E0C     + 64)                   // 513 ints (pad 2112)
#define OFF_E0OFS   (OFF_E0START + 2112)
#define OFF_E0CSRS  (OFF_E0OFS   + 2048)                 // E0CAP ints

#define WS_F(o)  ((float*)(ws + (o)))
#define WS_I(o)  ((int*)(ws + (o)))
#define WS_H(o)  ((unsigned long long*)(ws + (o)))

__device__ __forceinline__ bool lexless(float da, int ia, float db, int ib) {
  return (da < db) || (da == db && ia < ib);
}

__device__ __forceinline__ uint32_t hslot(unsigned long long key) {
  return (uint32_t)((key * 0x9E3779B97F4A7C15ull) >> 40) & HMASK;
}

// BN mean/rstd from analytic moments (cand moments in MOM + path moments pm*)
__device__ __forceinline__ void bn_from_moments(const char* ws,
    float w0, float w1, float cp, float clsF, float clsC,
    float pm0, float pm1, float pm00, float pm11, float pm01,
    float* meano, float* rstdo) {
  const float* M = (const float*)(ws + OFF_MOM);
  float sF0=M[0], sF1=M[1], sF00=M[2], sF11=M[3], sF01=M[4];
  float sC0=M[5], sC1=M[6], sC00=M[7], sC11=M[8], sC01=M[9];
  const float NC = (float)(NCND - NFREE);
  float sh  = w0*(sF0+sC0+pm0) + w1*(sF1+sC1+pm1)
            + (float)NFREE*clsF + NC*clsC + (float)PN*cp;
  float sh2 = w0*w0*(sF00+sC00+pm00) + w1*w1*(sF11+sC11+pm11)
            + 2.f*w0*w1*(sF01+sC01+pm01)
            + 2.f*w0*(clsF*sF0 + clsC*sC0 + cp*pm0)
            + 2.f*w1*(clsF*sF1 + clsC*sC1 + cp*pm1)
            + (float)NFREE*clsF*clsF + NC*clsC*clsC + (float)PN*cp*cp;
  float mean = sh  * (1.f / NNODE);
  float ex2  = sh2 * (1.f / NNODE);
  float var  = ex2 - mean * mean;
  *meano = mean;
  *rstdo = 1.0f / sqrtf(var + EPSV);
}

#define INSERT10(d2v, jv)                                                  \
  if (lexless((d2v), (jv), bd[9], bi[9])) {                                \
    bool placed = false;                                                   \
    _Pragma("unroll")                                                      \
    for (int k = 9; k > 0; k--) {                                          \
      bool shift = !placed && lexless((d2v), (jv), bd[k-1], bi[k-1]);      \
      bool here  = !placed && !shift;                                      \
      if (here)       { bd[k] = (d2v); bi[k] = (jv); placed = true; }      \
      else if (shift) { bd[k] = bd[k-1]; bi[k] = bi[k-1]; }                \
    }                                                                      \
    if (!placed) { bd[0] = (d2v); bi[0] = (jv); }                          \
  }

// wave top-10 pop-merge -> LDS slots [base..base+9] (lane r writes rank r)
#define WSTORE10(base) do {                                                \
    float cd[10]; int ci[10];                                              \
    _Pragma("unroll")                                                      \
    for (int k = 0; k < 10; k++) { cd[k] = bd[k]; ci[k] = bi[k]; }         \
    _Pragma("unroll")                                                      \
    for (int r = 0; r < 10; r++) {                                         \
      float md = cd[0]; int mi = ci[0];                                    \
      _Pragma("unroll")                                                    \
      for (int off = 32; off >= 1; off >>= 1) {                            \
        float od = __shfl_xor(md, off);                                    \
        int   oi = __shfl_xor(mi, off);                                    \
        if (lexless(od, oi, md, mi)) { md = od; mi = oi; }                 \
      }                                                                    \
      bool win = (cd[0] == md) && (ci[0] == mi);                           \
      if (win) {                                                           \
        _Pragma("unroll")                                                  \
        for (int k = 0; k < 9; k++) { cd[k] = cd[k+1]; ci[k] = ci[k+1]; }  \
        cd[9] = 3.4e38f; ci[9] = 0x7FFFFFFF;                               \
      }                                                                    \
      if (lane == r) { sD[(base)+r] = md; sI[(base)+r] = mi; }             \
    }                                                                      \
  } while (0)

// scan rows of box [xA..xB]x[yA..yB] with y % 4 == wv (4-wave split);
// each row is a contiguous scnd span, lanes stride it (coalesced).
#define SCAN_BOX4(xA, xB, yA, yB) do {                                     \
    for (int _y = (yA) + wv; _y <= (yB); _y += 4) {                        \
      int _s = cst[_y*GRID + (xA)], _e = cst[_y*GRID + (xB) + 1];          \
      for (int _t = _s + lane; _t < _e; _t += 64) {                        \
        float4 _q = scnd[_t];                                              \
        float _d2 = (psq + _q.z) - 2.f * fmaf(p1, _q.y, p0 * _q.x);        \
        int _j = __float_as_int(_q.w);                                     \
        INSERT10(_d2, _j);                                                 \
      }                                                                    \
    }                                                                      \
  } while (0)

// ---------------- setup kernels ----------------

__global__ __launch_bounds__(256) void k_init0(char* __restrict__ ws,
                                               const float* __restrict__ path_in) {
  unsigned i = blockIdx.x * 256u + threadIdx.x;       // grid = 65 → 16640 ids
  if (i < HSIZE)   WS_H(OFF_HASH)[i] = EMPTYK;
  if (i < NCELL+1) WS_I(OFF_CSTART)[i] = 0;
  if (i < 1024)    WS_F(OFF_PATH)[i] = path_in[i];
  if (i < 512)     WS_I(OFF_DEG0)[i] = 0;
  if (i < 16)      WS_F(OFF_MOM)[i] = 0.f;
  if (i == 0)      *WS_I(OFF_E0C) = 0;
}

// roles: b<NCB cand(pos/moments/hist) | b<NCB+NEB edge filter+dedup | last wprep
__global__ __launch_bounds__(256) void k_setupA(char* __restrict__ ws,
    const float* __restrict__ freep, const float* __restrict__ collp,
    const int* __restrict__ ei,
    const float* __restrict__ ncw1, const float* __restrict__ ncb1,
    const float* __restrict__ m0w1, const float* __restrict__ m0b1,
    const float* __restrict__ ncw2, const float* __restrict__ ncb2) {
  int b = blockIdx.x, tid = threadIdx.x;
  if (b < NCB) {
    __shared__ float s10[4][10];
    int j = b*256 + tid;
    bool valid = (j < NCND);
    float c0 = 0.f, c1 = 0.f;
    if (valid) {
      if (j < NFREE) { c0 = freep[2*j];          c1 = freep[2*j+1]; }
      else           { c0 = collp[2*(j-NFREE)];  c1 = collp[2*(j-NFREE)+1]; }
      ((float2*)(ws + OFF_CPOS))[j] = make_float2(c0, c1);
    }
    bool isF = valid && (j < NFREE), isC = valid && (j >= NFREE);
    float v[10];
    v[0]=isF?c0:0.f; v[1]=isF?c1:0.f; v[2]=isF?c0*c0:0.f; v[3]=isF?c1*c1:0.f; v[4]=isF?c0*c1:0.f;
    v[5]=isC?c0:0.f; v[6]=isC?c1:0.f; v[7]=isC?c0*c0:0.f; v[8]=isC?c1*c1:0.f; v[9]=isC?c0*c1:0.f;
    #pragma unroll
    for (int q = 0; q < 10; q++)
      #pragma unroll
      for (int off = 32; off >= 1; off >>= 1) v[q] += __shfl_xor(v[q], off);
    int wv = tid >> 6, lane = tid & 63;
    if (lane == 0) {
      #pragma unroll
      for (int q = 0; q < 10; q++) s10[wv][q] = v[q];
    }
    if (valid) {
      int cx = min(GRID-1, max(0, (int)((c0 - XMINF) * IVCW)));
      int cy = min(GRID-1, max(0, (int)((c1 - YMINF) * IVCW)));
      atomicAdd(&WS_I(OFF_CSTART)[cy*GRID + cx], 1);
    }
    __syncthreads();
    if (tid < 10)
      atomicAdd(&WS_F(OFF_MOM)[tid], s10[0][tid]+s10[1][tid]+s10[2][tid]+s10[3][tid]);
  } else if (b < NCB + NEB) {
    int e = (b - NCB)*256 + tid;
    if (e >= NEDGE) return;
    int src = ei[e], dst = ei[NEDGE + e];
    if (dst >= PN) return;                         // only dst<PN edges matter
    unsigned long long key = (unsigned long long)src * NNODE + (unsigned long long)dst;
    unsigned long long* hash = WS_H(OFF_HASH);
    uint32_t slot = hslot(key);
    for (;;) {
      unsigned long long prev = atomicCAS(&hash[slot], EMPTYK, key);
      if (prev == EMPTYK) {
        int pos = atomicAdd(WS_I(OFF_E0C), 1);
        if (pos < E0CAP) {
          WS_I(OFF_E0S)[pos] = src;
          WS_I(OFF_E0D)[pos] = dst;
          atomicAdd(&WS_I(OFF_DEG0)[dst], 1);
        }
        break;
      }
      if (prev == key) break;
      slot = (slot + 1) & HMASK;
    }
  } else {
    __shared__ float Wu[1024], Wv[1024];
    for (int it = 0; it < 4; it++) {
      int idx = it*256 + tid, k = idx >> 5, g = idx & 31;
      float a = m0w1[k*32+g], b2 = m0w1[(k+32)*32+g], c = m0w1[(k+64)*32+g];
      Wu[idx] = a + b2;  Wv[idx] = c - a;
    }
    __syncthreads();
    for (int it = 0; it < 4; it++) {
      int idx = it*256 + tid, k = idx >> 5, g = idx & 31;
      float au = 0.f, av = 0.f;
      #pragma unroll
      for (int f = 0; f < 32; f++) {
        float w2 = ncw2[k*32+f];
        au = fmaf(w2, Wu[f*32+g], au);
        av = fmaf(w2, Wv[f*32+g], av);
      }
      WS_F(OFF_WCU)[idx] = au;  WS_F(OFF_WCV)[idx] = av;
    }
    if (tid < 32) {
      float bu = 0.f, bv = 0.f;
      #pragma unroll
      for (int f = 0; f < 32; f++) {
        bu = fmaf(ncb2[f], Wu[f*32+tid], bu);
        bv = fmaf(ncb2[f], Wv[f*32+tid], bv);
      }
      WS_F(OFF_BU)[tid] = bu;
      WS_F(OFF_BV)[tid] = bv + m0b1[tid];        // fold mp0_b1 into dst-side
      WS_F(OFF_CPATH)[tid] = ncw1[64+tid]  + ncb1[tid];
      WS_F(OFF_CFREE)[tid] = ncw1[96+tid]  + ncb1[tid];
      WS_F(OFF_CCOL)[tid]  = ncw1[128+tid] + ncb1[tid];
    }
  }
}

// b==0: exclusive scan of cell counts | b==1: CSR build of fixed edges
__global__ __launch_bounds__(256) void k_scan2(char* __restrict__ ws) {
  int b = blockIdx.x, tid = threadIdx.x;
  if (b == 0) {
    __shared__ int part[256];
    int* cnt = WS_I(OFF_CSTART);
    int base = tid * (NCELL/256);
    int sum = 0;
    for (int k = 0; k < NCELL/256; k++) sum += cnt[base+k];
    part[tid] = sum;
    __syncthreads();
    for (int off = 1; off < 256; off <<= 1) {
      int t = (tid >= off) ? part[tid - off] : 0;
      __syncthreads();
      part[tid] += t;
      __syncthreads();
    }
    int run = part[tid] - sum;
    for (int k = 0; k < NCELL/256; k++) {
      int c = cnt[base+k];
      cnt[base+k] = run;
      WS_I(OFF_COFS)[base+k] = run;
      run += c;
    }
    if (tid == 255) cnt[NCELL] = run;
  } else {
    __shared__ int sc[512];
    sc[tid]     = WS_I(OFF_DEG0)[tid];
    sc[256+tid] = WS_I(OFF_DEG0)[256+tid];
    __syncthreads();
    if (tid == 0) {
      int run = 0;
      for (int i = 0; i < 512; i++) { int c = sc[i]; sc[i] = run; run += c; }
      WS_I(OFF_E0START)[512] = run;
    }
    __syncthreads();
    WS_I(OFF_E0START)[tid]     = sc[tid];
    WS_I(OFF_E0START)[256+tid] = sc[256+tid];
    WS_I(OFF_E0OFS)[tid]       = sc[tid];
    WS_I(OFF_E0OFS)[256+tid]   = sc[256+tid];
    __syncthreads();
    int n = *WS_I(OFF_E0C); if (n > E0CAP) n = E0CAP;
    for (int e = tid; e < n; e += 256) {
      int dst = WS_I(OFF_E0D)[e];
      int pos = atomicAdd(&WS_I(OFF_E0OFS)[dst], 1);
      WS_I(OFF_E0CSRS)[pos] = WS_I(OFF_E0S)[e];
    }
  }
}

__global__ __launch_bounds__(256) void k_scatter(char* __restrict__ ws) {
  int j = blockIdx.x * 256 + threadIdx.x;
  if (j >= NCND) return;
  float2 c = ((const float2*)(ws + OFF_CPOS))[j];
  int cx = min(GRID-1, max(0, (int)((c.x - XMINF) * IVCW)));
  int cy = min(GRID-1, max(0, (int)((c.y - YMINF) * IVCW)));
  int pos = atomicAdd(&WS_I(OFF_COFS)[cy*GRID + cx], 1);
  ((float4*)(ws + OFF_SCND))[pos] =
      make_float4(c.x, c.y, c.x*c.x + c.y*c.y, __int_as_float(j));
}

// ---------------- the fused per-loop kernel ----------------
// block = one path node, 256 threads (4 waves). Box scans split across the 4
// waves (row y -> wave y%4) for 4x memory-level parallelism; LDS rank-merge
// 40->10. Phase C skipped when its box is contained in the seed box (then the
// seed scan is already exact). Wave 0 does BN/S/epilogue as in R9.
__global__ __launch_bounds__(256) void k_loop(char* __restrict__ ws,
    const float* __restrict__ ncw1, const float* __restrict__ gamma,
    const float* __restrict__ beta, const float* __restrict__ ncw2,
    const float* __restrict__ ncb2, const float* __restrict__ m0w2,
    const float* __restrict__ m0b2, const float* __restrict__ m1w1,
    const float* __restrict__ m1b1, const float* __restrict__ m1w2,
    const float* __restrict__ m1b2, const float* __restrict__ snw,
    const float* __restrict__ snb, float* __restrict__ outp) {
  __shared__ float sD[40];
  __shared__ int   sI[40];
  __shared__ float sMD[10];
  __shared__ int   sMI[10];
  __shared__ int   sbox[9];           // xL,xR,yL,yR, xL2,xR2,yL2,yR2, skip
  int tid = threadIdx.x, lane = tid & 63, wv = tid >> 6;
  int node = blockIdx.x;
  float* pathb = WS_F(OFF_PATH);
  const float4* scnd = (const float4*)(ws + OFF_SCND);
  const int* cst = WS_I(OFF_CSTART);

  float p0 = pathb[2*node], p1 = pathb[2*node+1];
  float psq = p0*p0 + p1*p1;

  // ---- phase A (wave 0): grow square box until >=10 pts (prefix counts) ----
  if (wv == 0) {
    int cx = min(GRID-1, max(0, (int)((p0 - XMINF) * IVCW)));
    int cy = min(GRID-1, max(0, (int)((p1 - YMINF) * IVCW)));
    int R = 1, xL, xR, yL, yR;
    for (;;) {
      xL = max(cx - R, 0); xR = min(cx + R, GRID-1);
      yL = max(cy - R, 0); yR = min(cy + R, GRID-1);
      int cnt = 0;
      for (int y = yL + lane; y <= yR; y += 64)
        cnt += cst[y*GRID + xR + 1] - cst[y*GRID + xL];
      #pragma unroll
      for (int off = 32; off >= 1; off >>= 1) cnt += __shfl_xor(cnt, off);
      if (cnt >= KK || R >= GRID) break;
      R <<= 1;
    }
    if (lane == 0) { sbox[0]=xL; sbox[1]=xR; sbox[2]=yL; sbox[3]=yR; }
  }
  __syncthreads();
  int xL = sbox[0], xR = sbox[1], yL = sbox[2], yR = sbox[3];

  // ---- phase B: 4-wave split scan of seed box ----
  float bd[10]; int bi[10];
  #pragma unroll
  for (int k = 0; k < 10; k++) { bd[k] = 3.4e38f; bi[k] = 0x7FFFFFFF; }
  SCAN_BOX4(xL, xR, yL, yR);
  WSTORE10(wv*10);
  __syncthreads();

  // ---- merge 40 -> 10 (wave 0, lanes 0..39), exact rank by lex order ----
  if (wv == 0) {
    float de = (lane < 40) ? sD[lane] : 3.4e38f;
    int   ie = (lane < 40) ? sI[lane] : 0x7FFFFFFF;
    int rank = 0;
    for (int f = 0; f < 40; f++) {
      float df = sD[f]; int iff = sI[f];
      bool less = lexless(df, iff, de, ie) || (df == de && iff == ie && f < lane);
      rank += less ? 1 : 0;
    }
    if (lane < 40 && rank < 10) { sMD[rank] = de; sMI[rank] = ie; }
  }
  __syncthreads();
  // ---- phase C box + containment test (skip if seed scan already exact) ----
  if (tid == 0) {
    float r = sqrtf(sMD[9]) * 1.000002f;
    int xL2 = min(GRID-1, max(0, (int)((p0 - r - XMINF) * IVCW)));
    int xR2 = min(GRID-1, max(0, (int)((p0 + r - XMINF) * IVCW)));
    int yL2 = min(GRID-1, max(0, (int)((p1 - r - YMINF) * IVCW)));
    int yR2 = min(GRID-1, max(0, (int)((p1 + r - YMINF) * IVCW)));
    sbox[4]=xL2; sbox[5]=xR2; sbox[6]=yL2; sbox[7]=yR2;
    sbox[8] = (xL2 >= xL && xR2 <= xR && yL2 >= yL && yR2 <= yR) ? 1 : 0;
  }
  __syncthreads();
  if (!sbox[8]) {
    int xL2 = sbox[4], xR2 = sbox[5], yL2 = sbox[6], yR2 = sbox[7];
    #pragma unroll
    for (int k = 0; k < 10; k++) { bd[k] = 3.4e38f; bi[k] = 0x7FFFFFFF; }
    SCAN_BOX4(xL2, xR2, yL2, yR2);
    WSTORE10(wv*10);
    __syncthreads();
    if (wv == 0) {
      float de = (lane < 40) ? sD[lane] : 3.4e38f;
      int   ie = (lane < 40) ? sI[lane] : 0x7FFFFFFF;
      int rank = 0;
      for (int f = 0; f < 40; f++) {
        float df = sD[f]; int iff = sI[f];
        bool less = lexless(df, iff, de, ie) || (df == de && iff == ie && f < lane);
        rank += less ? 1 : 0;
      }
      if (lane < 40 && rank < 10) { sMD[rank] = de; sMI[rank] = ie; }
    }
    __syncthreads();
  }

  if (wv != 0) return;                 // waves 1..3 done (no more barriers)

  // ---- wave 0: dedup, BN, S, epilogue (as R9) ----
  int selIdx = (lane < KK) ? sMI[lane] : 0x7FFFFFFF;
  int s0 = WS_I(OFF_E0START)[node], s1 = WS_I(OFF_E0START)[node+1];
  int keep = 0;
  if (lane < KK) {
    int srcg = selIdx + PN;
    keep = 1;
    for (int t = s0; t < s1; t++)
      if (WS_I(OFF_E0CSRS)[t] == srcg) { keep = 0; break; }
  }
  unsigned long long kmask = __ballot(keep);
  int deg = (int)__popcll(kmask) + (s1 - s0);

  int fA = lane & 31;
  float w0 = ncw1[fA], w1 = ncw1[32+fA], cp = WS_F(OFF_CPATH)[fA];
  float clsF = WS_F(OFF_CFREE)[fA], clsC = WS_F(OFF_CCOL)[fA];
  float pm0=0,pm1=0,pm00=0,pm11=0,pm01=0;
  for (int r2 = lane; r2 < PN; r2 += 64) {
    float q0 = pathb[2*r2], q1 = pathb[2*r2+1];
    pm0+=q0; pm1+=q1; pm00+=q0*q0; pm11+=q1*q1; pm01+=q0*q1;
  }
  #pragma unroll
  for (int off = 32; off >= 1; off >>= 1) {
    pm0+=__shfl_xor(pm0,off); pm1+=__shfl_xor(pm1,off); pm00+=__shfl_xor(pm00,off);
    pm11+=__shfl_xor(pm11,off); pm01+=__shfl_xor(pm01,off);
  }
  float mean, rstd;
  bn_from_moments(ws, w0, w1, cp, clsF, clsC, pm0, pm1, pm00, pm11, pm01, &mean, &rstd);
  float gm = gamma[fA], bt = beta[fA];
  const float* wcu = WS_F(OFF_WCU); const float* wcv = WS_F(OFF_WCV);
  float buf = WS_F(OFF_BU)[fA];

  // xn_dst and v[dst]
  float hD = fmaf(p1, w1, fmaf(p0, w0, cp));
  float xnd = fmaf((hD - mean) * rstd, gm, bt);
  xnd = xnd > 0.f ? xnd : 0.f;
  float av = WS_F(OFF_BV)[fA];
  #pragma unroll
  for (int m = 0; m < 32; m++) av = fmaf(__shfl(xnd, m), wcv[m*32+fA], av);

  // S: kept kNN edges
  float S = 0.f;
  for (int k = 0; k < KK; k++) {
    if (!((kmask >> k) & 1ull)) continue;
    int jj = __shfl(selIdx, k);
    float c0 = WS_F(OFF_CPOS)[2*jj], c1 = WS_F(OFF_CPOS)[2*jj+1];
    float clsv = (jj < NFREE) ? clsF : clsC;
    float h = fmaf(c1, w1, fmaf(c0, w0, clsv));
    float xnf = fmaf((h - mean) * rstd, gm, bt);
    xnf = xnf > 0.f ? xnf : 0.f;
    float au = buf;
    #pragma unroll
    for (int m = 0; m < 32; m++) au = fmaf(__shfl(xnf, m), wcu[m*32+fA], au);
    float rr = au + av;
    if (rr > 0.f) S += rr;
  }
  // S: fixed edges
  for (int t = s0; t < s1; t++) {
    int src = WS_I(OFF_E0CSRS)[t];
    float q0, q1, clsv;
    if (src < PN) { q0 = pathb[2*src]; q1 = pathb[2*src+1]; clsv = cp; }
    else {
      int jj = src - PN;
      q0 = WS_F(OFF_CPOS)[2*jj]; q1 = WS_F(OFF_CPOS)[2*jj+1];
      clsv = (jj < NFREE) ? clsF : clsC;
    }
    float h = fmaf(q1, w1, fmaf(q0, w0, clsv));
    float xnf = fmaf((h - mean) * rstd, gm, bt);
    xnf = xnf > 0.f ? xnf : 0.f;
    float au = buf;
    #pragma unroll
    for (int m = 0; m < 32; m++) au = fmaf(__shfl(xnf, m), wcu[m*32+fA], au);
    float rr = au + av;
    if (rr > 0.f) S += rr;
  }

  // epilogue: four 32x32 GEMVs via shfl-dots
  float o = (float)deg * m0b2[fA];
  #pragma unroll
  for (int k = 0; k < 32; k++) o = fmaf(__shfl(S, k), m0w2[k*32+fA], o);
  float t1 = m1b1[fA];
  #pragma unroll
  for (int k = 0; k < 32; k++) t1 = fmaf(__shfl(o, k), m1w1[k*32+fA], t1);
  t1 = t1 > 0.f ? t1 : 0.f;
  float g2 = m1b2[fA];
  #pragma unroll
  for (int k = 0; k < 32; k++) g2 = fmaf(__shfl(t1, k), m1w2[k*32+fA], g2);
  float x = ncb2[fA];
  #pragma unroll
  for (int k = 0; k < 32; k++) x = fmaf(__shfl(xnd, k), ncw2[k*32+fA], x);
  float hh = x + g2;
  float r0 = hh * snw[2*fA], r1 = hh * snw[2*fA+1];
  #pragma unroll
  for (int off = 16; off >= 1; off >>= 1) {
    r0 += __shfl_xor(r0, off);
    r1 += __shfl_xor(r1, off);
  }
  if (lane == 0) {
    float np0, np1;
    if (node == 0 || node == PN-1) { np0 = p0; np1 = p1; }  // endpoints fixed
    else { np0 = snb[0] + r0; np1 = snb[1] + r1; }
    pathb[2*node]   = np0;
    pathb[2*node+1] = np1;
    outp[2*node]   = np0;
    outp[2*node+1] = np1;
  }
}

// ---------------- host launch ----------------

extern "C" void kernel_launch(void* const* d_in, const int* in_sizes, int n_in,
                              void* d_out, int out_size, void* d_ws, size_t ws_size,
                              hipStream_t stream) {
  const float* path  = (const float*)d_in[0];
  const float* freep = (const float*)d_in[1];
  const float* collp = (const float*)d_in[2];
  const int*   ei    = (const int*)d_in[4];
  const float* ncw1  = (const float*)d_in[6];
  const float* ncb1  = (const float*)d_in[7];
  const float* gamma = (const float*)d_in[8];
  const float* beta  = (const float*)d_in[9];
  const float* ncw2  = (const float*)d_in[10];
  const float* ncb2  = (const float*)d_in[11];
  const float* m0w1  = (const float*)d_in[12];
  const float* m0b1  = (const float*)d_in[13];
  const float* m0w2  = (const float*)d_in[14];
  const float* m0b2  = (const float*)d_in[15];
  const float* m1w1  = (const float*)d_in[16];
  const float* m1b1  = (const float*)d_in[17];
  const float* m1w2  = (const float*)d_in[18];
  const float* m1b2  = (const float*)d_in[19];
  const float* snw   = (const float*)d_in[20];
  const float* snb   = (const float*)d_in[21];
  char* ws = (char*)d_ws;

  k_init0  <<<65, 256, 0, stream>>>(ws, path);
  k_setupA <<<NCB + NEB + 1, 256, 0, stream>>>(ws, freep, collp, ei,
                                               ncw1, ncb1, m0w1, m0b1, ncw2, ncb2);
  k_scan2  <<<2, 256, 0, stream>>>(ws);
  k_scatter<<<NCB, 256, 0, stream>>>(ws);

  for (int l = 0; l < NLOOP; l++) {
    k_loop<<<PN, 256, 0, stream>>>(ws, ncw1, gamma, beta, ncw2, ncb2,
                                   m0w2, m0b2, m1w1, m1b1, m1w2, m1b2,
                                   snw, snb, (float*)d_out);
  }
}